// Round 9
// baseline (1603.815 us; speedup 1.0000x reference)
//
#include <hip/hip_runtime.h>
#include <stddef.h>
#include <stdint.h>

#define KTAPS 125

typedef _Float16 f16x8 __attribute__((ext_vector_type(8)));
typedef _Float16 f16x4 __attribute__((ext_vector_type(4)));
typedef float    f32x4 __attribute__((ext_vector_type(4)));

// ---------------- conv: register-direct fp16 MFMA, 4-deep pipeline, fp16 split-K partials
// Block 256 = 4 waves as 2(M)x2(N): wave = 32 rows x BN/2 cols.
// SWZ=1: 1-D grid, tap-range ts pinned to XCD (linear id % 8 == ts % 8 under round-robin);
//        all row-tiles of a tap-range share one XCD's L2 copy of those taps' weights.
// SWZ=0 (rt==1): grid (1, TS, CS) with ci-split for tail layers.
template<int NT>
__global__ __launch_bounds__(256) void subm_mfma(
    const _Float16* __restrict__ finh, const int* __restrict__ nbr,
    const _Float16* __restrict__ wt, _Float16* __restrict__ Pout,
    int N, int CinP, int TS, int CS, int SWZ)
{
    constexpr int BN = NT * 32;
    constexpr int DEPTH = (NT <= 5) ? 4 : 2;
    __shared__ int       nbs[16][64];
    __shared__ unsigned  msk[16][2];
    __shared__ unsigned char vtl[2][16];
    __shared__ int       vcs[2];
    __shared__ unsigned short sjc[2][128];

    const int tid  = threadIdx.x;
    const int lane = tid & 63;
    const int wid  = tid >> 6;
    const int wy   = wid & 1;
    const int wx   = wid >> 1;
    const int r15  = lane & 15;
    const int g4   = lane >> 4;

    int rowtile, ts, cs;
    if (SWZ) {
        int L   = blockIdx.x;
        int q   = L >> 3;
        int TSo = TS >> 3;                 // TS is a multiple of 8
        ts      = (L & 7) + 8 * (q % TSo);
        rowtile = q / TSo;
        cs      = 0;
    } else {
        rowtile = blockIdx.x; ts = blockIdx.y; cs = blockIdx.z;
    }

    const int row0 = rowtile * 64;
    const int k0   = (ts * KTAPS) / TS;
    const int k1   = ((ts + 1) * KTAPS) / TS;
    const int KR   = k1 - k0;             // <= 16 (TS >= 8)
    const int CC   = CinP >> 5;
    const int cc0  = (cs * CC) / CS;
    const int cc1  = ((cs + 1) * CC) / CS;
    const int NC   = cc1 - cc0;

    #pragma unroll
    for (int p = 0; p < 4; ++p) {
        int e = tid + p * 256;
        if (e < KR * 64) {
            int j = e >> 6, r = e & 63;
            int gr = row0 + r;
            nbs[j][r] = (gr < N) ? nbr[(size_t)gr * KTAPS + k0 + j] : -1;
        }
    }
    __syncthreads();
    for (int j = wid; j < KR; j += 4) {
        unsigned long long m = __ballot(nbs[j][lane] >= 0);
        if (lane == 0) { msk[j][0] = (unsigned)m; msk[j][1] = (unsigned)(m >> 32); }
    }
    __syncthreads();
    if (wid < 2) {
        int c = 0;
        for (int j = 0; j < KR; ++j)
            if (msk[j][wid]) { if (lane == 0) vtl[wid][c] = (unsigned char)j; ++c; }
        if (lane == 0) vcs[wid] = c;
        int TT = c * NC;
        for (int t = lane; t < TT; t += 64) {
            int j = vtl[wid][t / NC];
            int cc = cc0 + (t - (t / NC) * NC);
            sjc[wid][t] = (unsigned short)((j << 8) | cc);
        }
    }
    __syncthreads();
    const int T = vcs[wy] * NC;

    f32x4 acc[2][NT];
    #pragma unroll
    for (int mt = 0; mt < 2; ++mt)
        #pragma unroll
        for (int nf = 0; nf < NT; ++nf)
            acc[mt][nf] = (f32x4){0.f, 0.f, 0.f, 0.f};

    if (T > 0) {
        const size_t wchunk = (size_t)32 * BN;
        const int    boffh  = (g4 * BN + wx * (NT * 16) + r15) * 8;

        auto LOADA = [&](f16x8 (&a)[2], int j, int c) {
            unsigned mm = __builtin_amdgcn_readfirstlane(msk[j][wy]);
            if (mm & 0xFFFFu) {
                int src = nbs[j][wy * 32 + r15];
                if (src < 0) src = N;
                a[0] = *(const f16x8*)(finh + (size_t)src * CinP + c * 32 + g4 * 8);
            }
            if (mm >> 16) {
                int src = nbs[j][wy * 32 + 16 + r15];
                if (src < 0) src = N;
                a[1] = *(const f16x8*)(finh + (size_t)src * CinP + c * 32 + g4 * 8);
            }
        };
        auto LOADB = [&](f16x8 (&b)[NT], int j, int c) {
            const _Float16* base = wt + ((size_t)(k0 + j) * CC + c) * wchunk;
            #pragma unroll
            for (int nf = 0; nf < NT; ++nf)
                b[nf] = *(const f16x8*)&base[boffh + nf * 128];
        };
        auto LD = [&](f16x8 (&a)[2], f16x8 (&b)[NT], int t) {
            if (t < T) {
                int e = sjc[wy][t];
                int j = e >> 8, c = e & 255;
                LOADA(a, j, c); LOADB(b, j, c);
            }
        };
        auto CP = [&](f16x8 (&a)[2], f16x8 (&b)[NT], int t) {
            int j = sjc[wy][t] >> 8;
            unsigned mm = __builtin_amdgcn_readfirstlane(msk[j][wy]);
            if (mm & 0xFFFFu)
                #pragma unroll
                for (int nf = 0; nf < NT; ++nf)
                    acc[0][nf] = __builtin_amdgcn_mfma_f32_16x16x32_f16(a[0], b[nf], acc[0][nf], 0, 0, 0);
            if (mm >> 16)
                #pragma unroll
                for (int nf = 0; nf < NT; ++nf)
                    acc[1][nf] = __builtin_amdgcn_mfma_f32_16x16x32_f16(a[1], b[nf], acc[1][nf], 0, 0, 0);
        };

        if constexpr (DEPTH == 4) {
            f16x8 A0[2], B0[NT], A1[2], B1[NT], A2[2], B2[NT], A3[2], B3[NT];
            LD(A0, B0, 0); LD(A1, B1, 1); LD(A2, B2, 2); LD(A3, B3, 3);
            int t = 0;
            while (true) {
                CP(A0, B0, t); LD(A0, B0, t + 4); if (++t >= T) break;
                CP(A1, B1, t); LD(A1, B1, t + 4); if (++t >= T) break;
                CP(A2, B2, t); LD(A2, B2, t + 4); if (++t >= T) break;
                CP(A3, B3, t); LD(A3, B3, t + 4); if (++t >= T) break;
            }
        } else {
            f16x8 A0[2], B0[NT], A1[2], B1[NT];
            LD(A0, B0, 0); LD(A1, B1, 1);
            int t = 0;
            while (true) {
                CP(A0, B0, t); LD(A0, B0, t + 2); if (++t >= T) break;
                CP(A1, B1, t); LD(A1, B1, t + 2); if (++t >= T) break;
            }
        }
    }

    // store fp16 partial tile (always, even all-zero: reducer sums every slot)
    _Float16* base = Pout + (size_t)(ts * CS + cs) * ((size_t)N * BN);
    #pragma unroll
    for (int mt = 0; mt < 2; ++mt) {
        #pragma unroll
        for (int q = 0; q < 4; ++q) {
            int r = row0 + wy * 32 + mt * 16 + g4 * 4 + q;
            if (r < N) {
                #pragma unroll
                for (int nf = 0; nf < NT; ++nf)
                    base[(size_t)r * BN + wx * (NT * 16) + nf * 16 + r15] =
                        (_Float16)acc[mt][nf][q];
            }
        }
    }
}

// ---------------- reduceA: sum S fp16 partials -> fp16 features (scaled), pad zero row ---
__global__ __launch_bounds__(256) void reduce_a(
    const _Float16* __restrict__ P, _Float16* __restrict__ H,
    int N, int BN, int S, float scale)
{
    int idx = blockIdx.x * 256 + threadIdx.x;
    size_t i4 = (size_t)idx * 4;
    if (i4 >= (size_t)(N + 1) * BN) return;
    f16x4 h;
    if (i4 >= (size_t)N * BN) {
        h[0] = h[1] = h[2] = h[3] = (_Float16)0.f;
    } else {
        float s0 = 0.f, s1 = 0.f, s2 = 0.f, s3 = 0.f;
        size_t stride = (size_t)N * BN;
        for (int si = 0; si < S; ++si) {
            f16x4 p = *(const f16x4*)&P[si * stride + i4];
            s0 += (float)p[0]; s1 += (float)p[1]; s2 += (float)p[2]; s3 += (float)p[3];
        }
        h[0] = (_Float16)(s0 * scale); h[1] = (_Float16)(s1 * scale);
        h[2] = (_Float16)(s2 * scale); h[3] = (_Float16)(s3 * scale);
    }
    *(f16x4*)&H[i4] = h;
}

// ---------------- reduceB: sum S fp16 partials -> pool atomicMax (or final output) -------
__device__ __forceinline__ unsigned enc_f32(float f) {
    unsigned u = __float_as_uint(f);
    return (u & 0x80000000u) ? ~u : (u | 0x80000000u);
}

__global__ __launch_bounds__(256) void reduce_b(
    const _Float16* __restrict__ P, const int* __restrict__ pm,
    unsigned* __restrict__ ENC, float* __restrict__ dout,
    int N, int BN, int S, float fscale, int isLast)
{
    int idx = blockIdx.x * 256 + threadIdx.x;
    size_t i4 = (size_t)idx * 4;
    if (i4 >= (size_t)N * BN) return;
    float s0 = 0.f, s1 = 0.f, s2 = 0.f, s3 = 0.f;
    size_t stride = (size_t)N * BN;
    for (int si = 0; si < S; ++si) {
        f16x4 p = *(const f16x4*)&P[si * stride + i4];
        s0 += (float)p[0]; s1 += (float)p[1]; s2 += (float)p[2]; s3 += (float)p[3];
    }
    if (isLast) {
        dout[i4 + 0] = s0 * fscale; dout[i4 + 1] = s1 * fscale;
        dout[i4 + 2] = s2 * fscale; dout[i4 + 3] = s3 * fscale;
    } else {
        int row = (int)(i4 / BN), c = (int)(i4 % BN);
        unsigned* e = &ENC[(size_t)pm[row] * BN + c];
        atomicMax(e + 0, enc_f32(s0));
        atomicMax(e + 1, enc_f32(s1));
        atomicMax(e + 2, enc_f32(s2));
        atomicMax(e + 3, enc_f32(s3));
    }
}

// ---------------- pool decode: ENC -> fp16 features (scaled), re-zero ENC, pad row -------
__global__ __launch_bounds__(256) void pool_dec(
    unsigned* __restrict__ ENC, _Float16* __restrict__ H, int Nout, int C, float scale)
{
    int i = blockIdx.x * 256 + threadIdx.x;
    if (i < Nout * C) {
        unsigned u = ENC[i];
        float f = __uint_as_float((u & 0x80000000u) ? (u ^ 0x80000000u) : ~u);
        H[i] = (_Float16)(f * scale);
        ENC[i] = 0u;
    } else if (i < (Nout + 1) * C) {
        H[i] = (_Float16)0.f;
    }
}

// ---------------- per-level tap liveness flags ----------------
__global__ __launch_bounds__(256) void tap_flags(
    const int* n0, const int* n1, const int* n2, const int* n3,
    const int* n4, const int* n5, const int* n6,
    int N0, int N1, int N2, int N3, int N4, int N5, int N6,
    unsigned* __restrict__ flags)
{
    int l = blockIdx.y, k = blockIdx.x;
    const int* nb; int N;
    switch (l) {
        case 0: nb = n0; N = N0; break;  case 1: nb = n1; N = N1; break;
        case 2: nb = n2; N = N2; break;  case 3: nb = n3; N = N3; break;
        case 4: nb = n4; N = N4; break;  case 5: nb = n5; N = N5; break;
        default: nb = n6; N = N6; break;
    }
    bool any = false;
    for (int r = threadIdx.x; r < N; r += 256) any |= (nb[(size_t)r * KTAPS + k] >= 0);
    bool a = __syncthreads_or(any);
    if (threadIdx.x == 0) flags[l * KTAPS + k] = a ? 1u : 0u;
}

// ---------------- weight convert+transpose to MFMA fragment order ----------------
__global__ __launch_bounds__(256) void cvt_weights(
    const float* __restrict__ wa, const float* __restrict__ wb,
    _Float16* __restrict__ ta, _Float16* __restrict__ tb,
    const unsigned* __restrict__ flags,
    int CinA, int CCa, int CoutA, int splitA,
    int CinB, int CCb, int CoutB)
{
    int k = blockIdx.x;
    if (!flags[k]) return;
    int by = blockIdx.y;
    const float* w; _Float16* t; int Cin, CC, Cout, cc, c0;
    if (by < splitA) { w = wa; t = ta; Cin = CinA; CC = CCa; Cout = CoutA;
                       cc = by / (CoutA / 32); c0 = (by % (CoutA / 32)) * 32; }
    else { by -= splitA; w = wb; t = tb; Cin = CinB; CC = CCb; Cout = CoutB;
           cc = by / (CoutB / 32); c0 = (by % (CoutB / 32)) * 32; }

    __shared__ float T[32][33];
    int tid = threadIdx.x;
    #pragma unroll
    for (int p = 0; p < 4; ++p) {
        int e = tid + p * 256;
        int r = e >> 5, cl = e & 31;
        int ci = cc * 32 + r;
        T[r][cl] = (ci < Cin) ? w[((size_t)k * Cin + ci) * Cout + c0 + cl] : 0.f;
    }
    __syncthreads();
    if (tid < 128) {
        int g = tid >> 5, co = tid & 31;
        f16x8 h;
        #pragma unroll
        for (int j = 0; j < 8; ++j) h[j] = (_Float16)T[g * 8 + j][co];
        *(f16x8*)&t[((size_t)k * CC + cc) * (32 * (size_t)Cout) + ((size_t)g * Cout + c0 + co) * 8] = h;
    }
}

// ---------------- init: zero ENC, build padded fp16 level-0 features ----------------
__global__ __launch_bounds__(256) void init_all(
    const float* __restrict__ feat, _Float16* __restrict__ H,
    unsigned* __restrict__ ENC, int N0, int nE)
{
    int i = blockIdx.x * 256 + threadIdx.x;
    if (i < nE) ENC[i] = 0u;
    int nH = (N0 + 1) * 32;
    if (i < nH) {
        int r = i >> 5, cl = i & 31;
        H[i] = (r < N0 && cl < 3) ? (_Float16)feat[r * 3 + cl] : (_Float16)0.f;
    }
}

// ---------------- host ----------------
static inline int round8(int x) { int r = ((x + 4) / 8) * 8; if (r < 8) r = 8; if (r > 56) r = 56; return r; }

static void conv_dispatch(int NT, dim3 g, hipStream_t s, const _Float16* fin, const int* nbr,
                          const _Float16* wt, _Float16* P, int N, int CinP, int TS, int CS, int SWZ)
{
    switch (NT) {
        case 2: subm_mfma<2><<<g,256,0,s>>>(fin,nbr,wt,P,N,CinP,TS,CS,SWZ); break;
        case 3: subm_mfma<3><<<g,256,0,s>>>(fin,nbr,wt,P,N,CinP,TS,CS,SWZ); break;
        case 4: subm_mfma<4><<<g,256,0,s>>>(fin,nbr,wt,P,N,CinP,TS,CS,SWZ); break;
        case 5: subm_mfma<5><<<g,256,0,s>>>(fin,nbr,wt,P,N,CinP,TS,CS,SWZ); break;
        case 6: subm_mfma<6><<<g,256,0,s>>>(fin,nbr,wt,P,N,CinP,TS,CS,SWZ); break;
        case 7: subm_mfma<7><<<g,256,0,s>>>(fin,nbr,wt,P,N,CinP,TS,CS,SWZ); break;
        case 8: subm_mfma<8><<<g,256,0,s>>>(fin,nbr,wt,P,N,CinP,TS,CS,SWZ); break;
    }
}

extern "C" void kernel_launch(void* const* d_in, const int* in_sizes, int n_in,
                              void* d_out, int out_size, void* d_ws, size_t ws_size,
                              hipStream_t stream)
{
    const int* nbr[7]; const int* pm[6]; int Ns[7];
    {
        int idx = 0;
        for (int l = 0; l < 7; ++l) {
            nbr[l] = (const int*)d_in[idx];
            Ns[l]  = in_sizes[idx] / KTAPS;
            ++idx;
            if (l < 6) { pm[l] = (const int*)d_in[idx]; ++idx; }
        }
    }
    const float* w[14];
    for (int i = 0; i < 14; ++i) w[i] = (const float*)d_in[13 + i];
    const float* feat = (const float*)d_in[27];

    static const int CI[14]  = {3,64, 64,96, 96,128, 128,160, 160,192, 192,224, 224,256};
    static const int CO[14]  = {64,64, 96,96, 128,128, 160,160, 192,192, 224,224, 256,256};
    static const int KSH[14] = {0,3, 2,2, 1,1, 0,0, 0,1, 0,2, 2,3};   // cumulative sum = 17
    const float finalScale = 1.0f / 131072.0f;                        // 2^-17
    int CinP[14];
    for (int i = 0; i < 14; ++i) CinP[i] = (CI[i] < 32) ? 32 : CI[i];

    // per-conv split config + ws sizing
    int TSv[14], CSv[14], SWv[14];
    size_t maxP = 0, maxHa = 0, maxHb = 0, maxE = 0, maxWA = 0, maxWB = 0;
    for (int l = 0; l < 7; ++l) {
        int rt = (Ns[l] + 63) / 64;
        for (int q = 0; q < 2; ++q) {
            int i = 2 * l + q;
            if (rt > 1) { TSv[i] = round8(1024 / rt); CSv[i] = 1; SWv[i] = 1; }
            else        { TSv[i] = KTAPS; CSv[i] = CinP[i] / 32; SWv[i] = 0; }
            size_t p = (size_t)TSv[i] * CSv[i] * Ns[l] * CO[i];
            if (p > maxP) maxP = p;
        }
        size_t ha = (size_t)(Ns[l] + 1) * CinP[2*l];   if (ha > maxHa) maxHa = ha;
        size_t hb = (size_t)(Ns[l] + 1) * CinP[2*l+1]; if (hb > maxHb) maxHb = hb;
        if (l < 6) { size_t e = (size_t)Ns[l+1] * CO[2*l+1]; if (e > maxE) maxE = e; }
        size_t wa = (size_t)KTAPS * CinP[2*l] * CO[2*l];     if (wa > maxWA) maxWA = wa;
        size_t wb = (size_t)KTAPS * CinP[2*l+1] * CO[2*l+1]; if (wb > maxWB) maxWB = wb;
    }
    size_t off = 0;
    auto carve = [&](size_t bytes) -> void* {
        void* p = (char*)d_ws + off;
        off = (off + bytes + 255) & ~(size_t)255;
        return p;
    };
    _Float16*  P    = (_Float16*)carve(maxP * 2);
    _Float16*  Ha   = (_Float16*)carve(maxHa * 2);
    _Float16*  Hb   = (_Float16*)carve(maxHb * 2);
    unsigned*  ENC  = (unsigned*)carve(maxE * 4);
    _Float16*  wtA  = (_Float16*)carve(maxWA * 2);
    _Float16*  wtB  = (_Float16*)carve(maxWB * 2);
    unsigned*  flags= (unsigned*)carve(7 * KTAPS * 4);

    {
        int nMax = (int)maxE;
        int nH = (Ns[0] + 1) * 32;
        if (nH > nMax) nMax = nH;
        init_all<<<(nMax + 255) / 256, 256, 0, stream>>>(feat, Ha, ENC, Ns[0], (int)maxE);
    }
    tap_flags<<<dim3(KTAPS, 7), 256, 0, stream>>>(
        nbr[0], nbr[1], nbr[2], nbr[3], nbr[4], nbr[5], nbr[6],
        Ns[0], Ns[1], Ns[2], Ns[3], Ns[4], Ns[5], Ns[6], flags);

    for (int l = 0; l < 7; ++l) {
        int ia = 2 * l, ib = 2 * l + 1;
        int N = Ns[l];
        int rt = (N + 63) / 64;
        int splitA = (CinP[ia] / 32) * (CO[ia] / 32);
        int splitB = (CinP[ib] / 32) * (CO[ib] / 32);
        cvt_weights<<<dim3(KTAPS, splitA + splitB), 256, 0, stream>>>(
            w[ia], w[ib], wtA, wtB, flags + l * KTAPS,
            CI[ia], CinP[ia] / 32, CO[ia], splitA,
            CI[ib], CinP[ib] / 32, CO[ib]);

        // conv a: Ha -> P (S fp16 partials), reduce -> Hb fp16 (scaled for conv b)
        {
            int TS = TSv[ia], CS = CSv[ia], BN = CO[ia];
            dim3 g = SWv[ia] ? dim3(rt * TS) : dim3(rt, TS, CS);
            conv_dispatch(BN / 32, g, stream, Ha, nbr[l], wtA, P, N, CinP[ia], TS, CS, SWv[ia]);
            int tot = ((N + 1) * BN + 3) / 4;
            reduce_a<<<(tot + 255) / 256, 256, 0, stream>>>(P, Hb, N, BN, TS * CS,
                                                            (float)(1 << KSH[ib]));
        }
        // conv b: Hb -> P, reduce -> pool atomicMax (or final out)
        {
            int TS = TSv[ib], CS = CSv[ib], BN = CO[ib];
            dim3 g = SWv[ib] ? dim3(rt * TS) : dim3(rt, TS, CS);
            conv_dispatch(BN / 32, g, stream, Hb, nbr[l], wtB, P, N, CinP[ib], TS, CS, SWv[ib]);
            int tot = (N * BN + 3) / 4;
            reduce_b<<<(tot + 255) / 256, 256, 0, stream>>>(
                P, (l < 6) ? pm[l] : nullptr, ENC, (float*)d_out,
                N, BN, TS * CS, finalScale, (l == 6) ? 1 : 0);
        }
        if (l < 6) {
            int C = CO[ib], Nout = Ns[l + 1];
            int tot2 = (Nout + 1) * C;
            pool_dec<<<(tot2 + 255) / 256, 256, 0, stream>>>(ENC, Ha, Nout, C,
                                                             (float)(1 << KSH[2 * l + 2]));
        }
    }
}

// Round 10
// 438.607 us; speedup vs baseline: 3.6566x; 3.6566x over previous
//
#include <hip/hip_runtime.h>
#include <stddef.h>
#include <stdint.h>

#define KTAPS 125

typedef _Float16 f16x8 __attribute__((ext_vector_type(8)));
typedef _Float16 f16x4 __attribute__((ext_vector_type(4)));
typedef float    f32x4 __attribute__((ext_vector_type(4)));

// ---------------- conv: register-direct fp16 MFMA, 4-deep pipeline, fp16 split-K partials
// Block 256 = 4 waves as 2(M)x2(N): wave = 32 rows x BN/2 cols.
// SWZ=1: 1-D grid, tap-range ts pinned to XCD (linear id % 8 == ts % 8 under round-robin).
// SWZ=0 (rt==1): grid (1, TS, CS) with ci-split for tail layers.
template<int NT>
__global__ __launch_bounds__(256) void subm_mfma(
    const _Float16* __restrict__ finh, const int* __restrict__ nbr,
    const _Float16* __restrict__ wt, _Float16* __restrict__ Pout,
    int N, int CinP, int TS, int CS, int SWZ)
{
    constexpr int BN = NT * 32;
    constexpr int DEPTH = (NT <= 5) ? 4 : 2;
    __shared__ int       nbs[16][64];
    __shared__ unsigned  msk[16][2];
    __shared__ unsigned char vtl[2][16];
    __shared__ int       vcs[2];
    __shared__ unsigned short sjc[2][128];

    const int tid  = threadIdx.x;
    const int lane = tid & 63;
    const int wid  = tid >> 6;
    const int wy   = wid & 1;
    const int wx   = wid >> 1;
    const int r15  = lane & 15;
    const int g4   = lane >> 4;

    int rowtile, ts, cs;
    if (SWZ) {
        int L   = blockIdx.x;
        int q   = L >> 3;
        int TSo = TS >> 3;                 // TS is a multiple of 8
        ts      = (L & 7) + 8 * (q % TSo);
        rowtile = q / TSo;
        cs      = 0;
    } else {
        rowtile = blockIdx.x; ts = blockIdx.y; cs = blockIdx.z;
    }

    const int row0 = rowtile * 64;
    const int k0   = (ts * KTAPS) / TS;
    const int k1   = ((ts + 1) * KTAPS) / TS;
    const int KR   = k1 - k0;             // <= 16 (TS >= 8)
    const int CC   = CinP >> 5;
    const int cc0  = (cs * CC) / CS;
    const int cc1  = ((cs + 1) * CC) / CS;
    const int NC   = cc1 - cc0;

    #pragma unroll
    for (int p = 0; p < 4; ++p) {
        int e = tid + p * 256;
        if (e < KR * 64) {
            int j = e >> 6, r = e & 63;
            int gr = row0 + r;
            nbs[j][r] = (gr < N) ? nbr[(size_t)gr * KTAPS + k0 + j] : -1;
        }
    }
    __syncthreads();
    for (int j = wid; j < KR; j += 4) {
        unsigned long long m = __ballot(nbs[j][lane] >= 0);
        if (lane == 0) { msk[j][0] = (unsigned)m; msk[j][1] = (unsigned)(m >> 32); }
    }
    __syncthreads();
    if (wid < 2) {
        int c = 0;
        for (int j = 0; j < KR; ++j)
            if (msk[j][wid]) { if (lane == 0) vtl[wid][c] = (unsigned char)j; ++c; }
        if (lane == 0) vcs[wid] = c;
        int TT = c * NC;
        for (int t = lane; t < TT; t += 64) {
            int j = vtl[wid][t / NC];
            int cc = cc0 + (t - (t / NC) * NC);
            sjc[wid][t] = (unsigned short)((j << 8) | cc);
        }
    }
    __syncthreads();
    const int T = vcs[wy] * NC;

    f32x4 acc[2][NT];
    #pragma unroll
    for (int mt = 0; mt < 2; ++mt)
        #pragma unroll
        for (int nf = 0; nf < NT; ++nf)
            acc[mt][nf] = (f32x4){0.f, 0.f, 0.f, 0.f};

    if (T > 0) {
        const size_t wchunk = (size_t)32 * BN;
        const int    boffh  = (g4 * BN + wx * (NT * 16) + r15) * 8;

        auto LOADA = [&](f16x8 (&a)[2], int j, int c) {
            unsigned mm = __builtin_amdgcn_readfirstlane(msk[j][wy]);
            if (mm & 0xFFFFu) {
                int src = nbs[j][wy * 32 + r15];
                if (src < 0) src = N;
                a[0] = *(const f16x8*)(finh + (size_t)src * CinP + c * 32 + g4 * 8);
            }
            if (mm >> 16) {
                int src = nbs[j][wy * 32 + 16 + r15];
                if (src < 0) src = N;
                a[1] = *(const f16x8*)(finh + (size_t)src * CinP + c * 32 + g4 * 8);
            }
        };
        auto LOADB = [&](f16x8 (&b)[NT], int j, int c) {
            const _Float16* base = wt + ((size_t)(k0 + j) * CC + c) * wchunk;
            #pragma unroll
            for (int nf = 0; nf < NT; ++nf)
                b[nf] = *(const f16x8*)&base[boffh + nf * 128];
        };
        auto LD = [&](f16x8 (&a)[2], f16x8 (&b)[NT], int t) {
            if (t < T) {
                int e = sjc[wy][t];
                int j = e >> 8, c = e & 255;
                LOADA(a, j, c); LOADB(b, j, c);
            }
        };
        auto CP = [&](f16x8 (&a)[2], f16x8 (&b)[NT], int t) {
            int j = sjc[wy][t] >> 8;
            unsigned mm = __builtin_amdgcn_readfirstlane(msk[j][wy]);
            if (mm & 0xFFFFu)
                #pragma unroll
                for (int nf = 0; nf < NT; ++nf)
                    acc[0][nf] = __builtin_amdgcn_mfma_f32_16x16x32_f16(a[0], b[nf], acc[0][nf], 0, 0, 0);
            if (mm >> 16)
                #pragma unroll
                for (int nf = 0; nf < NT; ++nf)
                    acc[1][nf] = __builtin_amdgcn_mfma_f32_16x16x32_f16(a[1], b[nf], acc[1][nf], 0, 0, 0);
        };

        if constexpr (DEPTH == 4) {
            f16x8 A0[2], B0[NT], A1[2], B1[NT], A2[2], B2[NT], A3[2], B3[NT];
            LD(A0, B0, 0); LD(A1, B1, 1); LD(A2, B2, 2); LD(A3, B3, 3);
            int t = 0;
            while (true) {
                CP(A0, B0, t); LD(A0, B0, t + 4); if (++t >= T) break;
                CP(A1, B1, t); LD(A1, B1, t + 4); if (++t >= T) break;
                CP(A2, B2, t); LD(A2, B2, t + 4); if (++t >= T) break;
                CP(A3, B3, t); LD(A3, B3, t + 4); if (++t >= T) break;
            }
        } else {
            f16x8 A0[2], B0[NT], A1[2], B1[NT];
            LD(A0, B0, 0); LD(A1, B1, 1);
            int t = 0;
            while (true) {
                CP(A0, B0, t); LD(A0, B0, t + 2); if (++t >= T) break;
                CP(A1, B1, t); LD(A1, B1, t + 2); if (++t >= T) break;
            }
        }
    }

    // store fp16 partial tile (always, even all-zero: reducer sums every slot)
    _Float16* base = Pout + (size_t)(ts * CS + cs) * ((size_t)N * BN);
    #pragma unroll
    for (int mt = 0; mt < 2; ++mt) {
        #pragma unroll
        for (int q = 0; q < 4; ++q) {
            int r = row0 + wy * 32 + mt * 16 + g4 * 4 + q;
            if (r < N) {
                #pragma unroll
                for (int nf = 0; nf < NT; ++nf)
                    base[(size_t)r * BN + wx * (NT * 16) + nf * 16 + r15] =
                        (_Float16)acc[mt][nf][q];
            }
        }
    }
}

// ---------------- slot-parallel reducers: 16 quads x 16 slot-stripes per block -----------
// reduceA: sum S fp16 partials -> fp16 features (scaled), pad zero row
__global__ __launch_bounds__(256) void reduce_a(
    const _Float16* __restrict__ P, _Float16* __restrict__ H,
    int N, int BN, int S, float scale)
{
    const int qi = threadIdx.x & 15;
    const int st = threadIdx.x >> 4;
    const int q  = blockIdx.x * 16 + qi;
    const size_t i4  = (size_t)q * 4;
    const size_t tot = (size_t)N * BN;
    f32x4 s = (f32x4){0.f, 0.f, 0.f, 0.f};
    if (i4 < tot) {
        for (int si = st; si < S; si += 16) {
            f16x4 p = *(const f16x4*)&P[(size_t)si * tot + i4];
            s[0] += (float)p[0]; s[1] += (float)p[1];
            s[2] += (float)p[2]; s[3] += (float)p[3];
        }
    }
    __shared__ f32x4 red[16][16];
    red[st][qi] = s;
    __syncthreads();
    #pragma unroll
    for (int off = 8; off > 0; off >>= 1) {
        if (st < off) red[st][qi] += red[st + off][qi];
        __syncthreads();
    }
    if (st == 0 && i4 < (size_t)(N + 1) * BN) {
        f32x4 r = red[0][qi];
        f16x4 h;
        h[0] = (_Float16)(r[0] * scale); h[1] = (_Float16)(r[1] * scale);
        h[2] = (_Float16)(r[2] * scale); h[3] = (_Float16)(r[3] * scale);
        *(f16x4*)&H[i4] = h;
    }
}

// reduceB: sum S fp16 partials -> pool atomicMax (or final output)
__device__ __forceinline__ unsigned enc_f32(float f) {
    unsigned u = __float_as_uint(f);
    return (u & 0x80000000u) ? ~u : (u | 0x80000000u);
}

__global__ __launch_bounds__(256) void reduce_b(
    const _Float16* __restrict__ P, const int* __restrict__ pm,
    unsigned* __restrict__ ENC, float* __restrict__ dout,
    int N, int BN, int S, float fscale, int isLast)
{
    const int qi = threadIdx.x & 15;
    const int st = threadIdx.x >> 4;
    const int q  = blockIdx.x * 16 + qi;
    const size_t i4  = (size_t)q * 4;
    const size_t tot = (size_t)N * BN;
    f32x4 s = (f32x4){0.f, 0.f, 0.f, 0.f};
    if (i4 < tot) {
        for (int si = st; si < S; si += 16) {
            f16x4 p = *(const f16x4*)&P[(size_t)si * tot + i4];
            s[0] += (float)p[0]; s[1] += (float)p[1];
            s[2] += (float)p[2]; s[3] += (float)p[3];
        }
    }
    __shared__ f32x4 red[16][16];
    red[st][qi] = s;
    __syncthreads();
    #pragma unroll
    for (int off = 8; off > 0; off >>= 1) {
        if (st < off) red[st][qi] += red[st + off][qi];
        __syncthreads();
    }
    if (st == 0 && i4 < tot) {
        f32x4 r = red[0][qi];
        if (isLast) {
            dout[i4 + 0] = r[0] * fscale; dout[i4 + 1] = r[1] * fscale;
            dout[i4 + 2] = r[2] * fscale; dout[i4 + 3] = r[3] * fscale;
        } else {
            int row = (int)(i4 / BN), c = (int)(i4 % BN);
            unsigned* e = &ENC[(size_t)pm[row] * BN + c];
            atomicMax(e + 0, enc_f32(r[0]));
            atomicMax(e + 1, enc_f32(r[1]));
            atomicMax(e + 2, enc_f32(r[2]));
            atomicMax(e + 3, enc_f32(r[3]));
        }
    }
}

// ---------------- pool decode: ENC -> fp16 features (scaled), re-zero ENC, pad row -------
__global__ __launch_bounds__(256) void pool_dec(
    unsigned* __restrict__ ENC, _Float16* __restrict__ H, int Nout, int C, float scale)
{
    int i = blockIdx.x * 256 + threadIdx.x;
    if (i < Nout * C) {
        unsigned u = ENC[i];
        float f = __uint_as_float((u & 0x80000000u) ? (u ^ 0x80000000u) : ~u);
        H[i] = (_Float16)(f * scale);
        ENC[i] = 0u;
    } else if (i < (Nout + 1) * C) {
        H[i] = (_Float16)0.f;
    }
}

// ---------------- per-level tap liveness flags ----------------
__global__ __launch_bounds__(256) void tap_flags(
    const int* n0, const int* n1, const int* n2, const int* n3,
    const int* n4, const int* n5, const int* n6,
    int N0, int N1, int N2, int N3, int N4, int N5, int N6,
    unsigned* __restrict__ flags)
{
    int l = blockIdx.y, k = blockIdx.x;
    const int* nb; int N;
    switch (l) {
        case 0: nb = n0; N = N0; break;  case 1: nb = n1; N = N1; break;
        case 2: nb = n2; N = N2; break;  case 3: nb = n3; N = N3; break;
        case 4: nb = n4; N = N4; break;  case 5: nb = n5; N = N5; break;
        default: nb = n6; N = N6; break;
    }
    bool any = false;
    for (int r = threadIdx.x; r < N; r += 256) any |= (nb[(size_t)r * KTAPS + k] >= 0);
    bool a = __syncthreads_or(any);
    if (threadIdx.x == 0) flags[l * KTAPS + k] = a ? 1u : 0u;
}

// ---------------- weight convert+transpose to MFMA fragment order ----------------
__global__ __launch_bounds__(256) void cvt_weights(
    const float* __restrict__ wa, const float* __restrict__ wb,
    _Float16* __restrict__ ta, _Float16* __restrict__ tb,
    const unsigned* __restrict__ flags,
    int CinA, int CCa, int CoutA, int splitA,
    int CinB, int CCb, int CoutB)
{
    int k = blockIdx.x;
    if (!flags[k]) return;
    int by = blockIdx.y;
    const float* w; _Float16* t; int Cin, CC, Cout, cc, c0;
    if (by < splitA) { w = wa; t = ta; Cin = CinA; CC = CCa; Cout = CoutA;
                       cc = by / (CoutA / 32); c0 = (by % (CoutA / 32)) * 32; }
    else { by -= splitA; w = wb; t = tb; Cin = CinB; CC = CCb; Cout = CoutB;
           cc = by / (CoutB / 32); c0 = (by % (CoutB / 32)) * 32; }

    __shared__ float T[32][33];
    int tid = threadIdx.x;
    #pragma unroll
    for (int p = 0; p < 4; ++p) {
        int e = tid + p * 256;
        int r = e >> 5, cl = e & 31;
        int ci = cc * 32 + r;
        T[r][cl] = (ci < Cin) ? w[((size_t)k * Cin + ci) * Cout + c0 + cl] : 0.f;
    }
    __syncthreads();
    if (tid < 128) {
        int g = tid >> 5, co = tid & 31;
        f16x8 h;
        #pragma unroll
        for (int j = 0; j < 8; ++j) h[j] = (_Float16)T[g * 8 + j][co];
        *(f16x8*)&t[((size_t)k * CC + cc) * (32 * (size_t)Cout) + ((size_t)g * Cout + c0 + co) * 8] = h;
    }
}

// ---------------- init: zero ENC, build padded fp16 level-0 features ----------------
__global__ __launch_bounds__(256) void init_all(
    const float* __restrict__ feat, _Float16* __restrict__ H,
    unsigned* __restrict__ ENC, int N0, int nE)
{
    int i = blockIdx.x * 256 + threadIdx.x;
    if (i < nE) ENC[i] = 0u;
    int nH = (N0 + 1) * 32;
    if (i < nH) {
        int r = i >> 5, cl = i & 31;
        H[i] = (r < N0 && cl < 3) ? (_Float16)feat[r * 3 + cl] : (_Float16)0.f;
    }
}

// ---------------- host ----------------
static inline int round8(int x) { int r = ((x + 4) / 8) * 8; if (r < 8) r = 8; if (r > 56) r = 56; return r; }

static void conv_dispatch(int NT, dim3 g, hipStream_t s, const _Float16* fin, const int* nbr,
                          const _Float16* wt, _Float16* P, int N, int CinP, int TS, int CS, int SWZ)
{
    switch (NT) {
        case 2: subm_mfma<2><<<g,256,0,s>>>(fin,nbr,wt,P,N,CinP,TS,CS,SWZ); break;
        case 3: subm_mfma<3><<<g,256,0,s>>>(fin,nbr,wt,P,N,CinP,TS,CS,SWZ); break;
        case 4: subm_mfma<4><<<g,256,0,s>>>(fin,nbr,wt,P,N,CinP,TS,CS,SWZ); break;
        case 5: subm_mfma<5><<<g,256,0,s>>>(fin,nbr,wt,P,N,CinP,TS,CS,SWZ); break;
        case 6: subm_mfma<6><<<g,256,0,s>>>(fin,nbr,wt,P,N,CinP,TS,CS,SWZ); break;
        case 7: subm_mfma<7><<<g,256,0,s>>>(fin,nbr,wt,P,N,CinP,TS,CS,SWZ); break;
        case 8: subm_mfma<8><<<g,256,0,s>>>(fin,nbr,wt,P,N,CinP,TS,CS,SWZ); break;
    }
}

extern "C" void kernel_launch(void* const* d_in, const int* in_sizes, int n_in,
                              void* d_out, int out_size, void* d_ws, size_t ws_size,
                              hipStream_t stream)
{
    const int* nbr[7]; const int* pm[6]; int Ns[7];
    {
        int idx = 0;
        for (int l = 0; l < 7; ++l) {
            nbr[l] = (const int*)d_in[idx];
            Ns[l]  = in_sizes[idx] / KTAPS;
            ++idx;
            if (l < 6) { pm[l] = (const int*)d_in[idx]; ++idx; }
        }
    }
    const float* w[14];
    for (int i = 0; i < 14; ++i) w[i] = (const float*)d_in[13 + i];
    const float* feat = (const float*)d_in[27];

    static const int CI[14]  = {3,64, 64,96, 96,128, 128,160, 160,192, 192,224, 224,256};
    static const int CO[14]  = {64,64, 96,96, 128,128, 160,160, 192,192, 224,224, 256,256};
    static const int KSH[14] = {0,3, 2,2, 1,1, 0,0, 0,1, 0,2, 2,3};   // cumulative sum = 17
    const float finalScale = 1.0f / 131072.0f;                        // 2^-17
    int CinP[14];
    for (int i = 0; i < 14; ++i) CinP[i] = (CI[i] < 32) ? 32 : CI[i];

    // per-conv split config + ws sizing
    int TSv[14], CSv[14], SWv[14];
    size_t maxP = 0, maxHa = 0, maxHb = 0, maxE = 0, maxWA = 0, maxWB = 0;
    for (int l = 0; l < 7; ++l) {
        int rt = (Ns[l] + 63) / 64;
        for (int q = 0; q < 2; ++q) {
            int i = 2 * l + q;
            if (rt > 1) { TSv[i] = round8(1024 / rt); CSv[i] = 1; SWv[i] = 1; }
            else        { TSv[i] = KTAPS; CSv[i] = CinP[i] / 32; SWv[i] = 0; }
            size_t p = (size_t)TSv[i] * CSv[i] * Ns[l] * CO[i];
            if (p > maxP) maxP = p;
        }
        size_t ha = (size_t)(Ns[l] + 1) * CinP[2*l];   if (ha > maxHa) maxHa = ha;
        size_t hb = (size_t)(Ns[l] + 1) * CinP[2*l+1]; if (hb > maxHb) maxHb = hb;
        if (l < 6) { size_t e = (size_t)Ns[l+1] * CO[2*l+1]; if (e > maxE) maxE = e; }
        size_t wa = (size_t)KTAPS * CinP[2*l] * CO[2*l];     if (wa > maxWA) maxWA = wa;
        size_t wb = (size_t)KTAPS * CinP[2*l+1] * CO[2*l+1]; if (wb > maxWB) maxWB = wb;
    }
    size_t off = 0;
    auto carve = [&](size_t bytes) -> void* {
        void* p = (char*)d_ws + off;
        off = (off + bytes + 255) & ~(size_t)255;
        return p;
    };
    _Float16*  P    = (_Float16*)carve(maxP * 2);
    _Float16*  Ha   = (_Float16*)carve(maxHa * 2);
    _Float16*  Hb   = (_Float16*)carve(maxHb * 2);
    unsigned*  ENC  = (unsigned*)carve(maxE * 4);
    _Float16*  wtA  = (_Float16*)carve(maxWA * 2);
    _Float16*  wtB  = (_Float16*)carve(maxWB * 2);
    unsigned*  flags= (unsigned*)carve(7 * KTAPS * 4);

    {
        int nMax = (int)maxE;
        int nH = (Ns[0] + 1) * 32;
        if (nH > nMax) nMax = nH;
        init_all<<<(nMax + 255) / 256, 256, 0, stream>>>(feat, Ha, ENC, Ns[0], (int)maxE);
    }
    tap_flags<<<dim3(KTAPS, 7), 256, 0, stream>>>(
        nbr[0], nbr[1], nbr[2], nbr[3], nbr[4], nbr[5], nbr[6],
        Ns[0], Ns[1], Ns[2], Ns[3], Ns[4], Ns[5], Ns[6], flags);

    for (int l = 0; l < 7; ++l) {
        int ia = 2 * l, ib = 2 * l + 1;
        int N = Ns[l];
        int rt = (N + 63) / 64;
        int splitA = (CinP[ia] / 32) * (CO[ia] / 32);
        int splitB = (CinP[ib] / 32) * (CO[ib] / 32);
        cvt_weights<<<dim3(KTAPS, splitA + splitB), 256, 0, stream>>>(
            w[ia], w[ib], wtA, wtB, flags + l * KTAPS,
            CI[ia], CinP[ia] / 32, CO[ia], splitA,
            CI[ib], CinP[ib] / 32, CO[ib]);

        // conv a: Ha -> P (S fp16 partials), reduce -> Hb fp16 (scaled for conv b)
        {
            int TS = TSv[ia], CS = CSv[ia], BN = CO[ia];
            dim3 g = SWv[ia] ? dim3(rt * TS) : dim3(rt, TS, CS);
            conv_dispatch(BN / 32, g, stream, Ha, nbr[l], wtA, P, N, CinP[ia], TS, CS, SWv[ia]);
            int quads = ((N + 1) * BN) / 4;
            reduce_a<<<(quads + 15) / 16, 256, 0, stream>>>(P, Hb, N, BN, TS * CS,
                                                            (float)(1 << KSH[ib]));
        }
        // conv b: Hb -> P, reduce -> pool atomicMax (or final out)
        {
            int TS = TSv[ib], CS = CSv[ib], BN = CO[ib];
            dim3 g = SWv[ib] ? dim3(rt * TS) : dim3(rt, TS, CS);
            conv_dispatch(BN / 32, g, stream, Hb, nbr[l], wtB, P, N, CinP[ib], TS, CS, SWv[ib]);
            int quads = (N * BN) / 4;
            reduce_b<<<(quads + 15) / 16, 256, 0, stream>>>(
                P, (l < 6) ? pm[l] : nullptr, ENC, (float*)d_out,
                N, BN, TS * CS, finalScale, (l == 6) ? 1 : 0);
        }
        if (l < 6) {
            int C = CO[ib], Nout = Ns[l + 1];
            int tot2 = (Nout + 1) * C;
            pool_dec<<<(tot2 + 255) / 256, 256, 0, stream>>>(ENC, Ha, Nout, C,
                                                             (float)(1 << KSH[2 * l + 2]));
        }
    }
}